// Round 13
// baseline (53.506 us; speedup 1.0000x reference)
//
#include <hip/hip_runtime.h>

#define HW 25600
#define TS 16   // spatial locations per tile
#define NT 1600 // total tiles
#define NB 256  // persistent blocks (1 per CU; LDS forces 1 block/CU)
#define TPX 200 // tiles per XCD pool

typedef float  f32x4   __attribute__((ext_vector_type(4)));
typedef short  short8  __attribute__((ext_vector_type(8)));
typedef short  short4v __attribute__((ext_vector_type(4)));
typedef unsigned int uint2v __attribute__((ext_vector_type(2)));
typedef unsigned int uint4v __attribute__((ext_vector_type(4)));

__device__ __forceinline__ float bf2f(short h) {
    return __builtin_bit_cast(float, (unsigned)((unsigned short)h) << 16);
}
// HW packed f32->bf16 (RNE): D.lo = bf16(a), D.hi = bf16(b)
__device__ __forceinline__ unsigned cvt_pk(float a, float b) {
    unsigned r;
    asm("v_cvt_pk_bf16_f32 %0, %1, %2" : "=v"(r) : "v"(a), "v"(b));
    return r;
}

typedef __attribute__((address_space(3))) const char lds_cchar;
typedef __attribute__((address_space(3))) char lds_char;
typedef __attribute__((address_space(1))) const void g_cvoid;
__device__ __forceinline__ unsigned lds_u32(const void* p) {
    return (unsigned)(uintptr_t)(lds_cchar*)p;
}
// Async global->LDS DMA, 16B/lane. Dest = lds_base + lane*16 (linear);
// global source address is per-lane. No VGPR destination => no spill pressure.
__device__ __forceinline__ void dma16(const float* g, unsigned lds_byte) {
    __builtin_amdgcn_global_load_lds(
        (g_cvoid*)g,
        (__attribute__((address_space(3))) void*)(lds_char*)(uintptr_t)lds_byte,
        16, 0, 0);
}

// ds_read_b64_tr_b16: lane addr = tile_base(128B-aligned) + lane16*8.
// Elem j = bf16 at tile_base + lane16*2 + j*32. offset:128 -> next 4 rows.
__device__ __forceinline__ short4v tr_read(unsigned a) {
    short4v d;
    asm volatile("ds_read_b64_tr_b16 %0, %1" : "=v"(d) : "v"(a) : "memory");
    return d;
}
__device__ __forceinline__ short4v tr_read128(unsigned a) {
    short4v d;
    asm volatile("ds_read_b64_tr_b16 %0, %1 offset:128" : "=v"(d) : "v"(a) : "memory");
    return d;
}
__device__ __forceinline__ uint4v lds_b128(unsigned a) {
    uint4v d;
    asm volatile("ds_read_b128 %0, %1" : "=v"(d) : "v"(a) : "memory");
    return d;
}
// Counted lgkm waits for the 2-deep DS pipelines (rule #18: SB(0) after).
__device__ __forceinline__ void wait_lgkm8() {
    asm volatile("s_waitcnt lgkmcnt(8)" ::: "memory");
    __builtin_amdgcn_sched_barrier(0);
}
__device__ __forceinline__ void wait_lgkm6() {
    asm volatile("s_waitcnt lgkmcnt(6)" ::: "memory");
    __builtin_amdgcn_sched_barrier(0);
}
__device__ __forceinline__ void wait_lgkm0() {
    asm volatile("s_waitcnt lgkmcnt(0)" ::: "memory");
    __builtin_amdgcn_sched_barrier(0);
}
__device__ __forceinline__ void wait_vm0() {
    asm volatile("s_waitcnt vmcnt(0)" ::: "memory");
    __builtin_amdgcn_sched_barrier(0);
}
// Barrier that drains only LDS ops; VMEM (DMA, stores) stays in flight.
__device__ __forceinline__ void bar_lgkm() {
    asm volatile("s_waitcnt lgkmcnt(0)" ::: "memory");
    __builtin_amdgcn_s_barrier();
    asm volatile("" ::: "memory");
}

// 8-read tr cluster: 4 tiles (t=0..3) x (lo, hi)
struct Clu { short4v lo0, hi0, lo1, hi1, lo2, hi2, lo3, hi3; };
__device__ __forceinline__ void issue_clu(Clu& C, unsigned base, int tstride) {
    C.lo0 = tr_read(base);                C.hi0 = tr_read128(base);
    C.lo1 = tr_read(base + tstride);      C.hi1 = tr_read128(base + tstride);
    C.lo2 = tr_read(base + 2 * tstride);  C.hi2 = tr_read128(base + 2 * tstride);
    C.lo3 = tr_read(base + 3 * tstride);  C.hi3 = tr_read128(base + 3 * tstride);
}
__device__ __forceinline__ short8 mk8(short4v lo, short4v hi) {
    return __builtin_shufflevector(lo, hi, 0, 1, 2, 3, 4, 5, 6, 7);
}

// LDS layout (bytes), 133136 total (1 block/CU):
//  Xf32 [4096] float4      0      .. 65536   DMA landing buffer (f32, linear)
//  Xbf  [4][256][16] bf16   65536  .. 98304   feats (b-major), bf16
//  fbf  [64][128]   bf16    98304  .. 114688  f (conv out), swizzle c^(s<<3)^(t<<5)
//  Rbf  [4][128][16] bf16   114688 .. 131072  retrieved
//  sc   [32][16]    f32     131072 .. 133120  attn weights
//  tsl  [4] int             133120 .. 133136  tile-queue broadcast slots
__global__ __launch_bounds__(512, 2) void mmf_kernel(
    const float* __restrict__ feat0, const float* __restrict__ feat1,
    const float* __restrict__ adapter, const float* __restrict__ conv_w,
    const float* __restrict__ conv_b, const float* __restrict__ mlp_w,
    const float* __restrict__ mlp_b, float* __restrict__ out,
    int* __restrict__ cnt)
{
    __shared__ __align__(128) char smem[133136];
    float* Xf32 = (float*)smem;
    short* Xbf  = (short*)(smem + 65536);
    short* fbf  = (short*)(smem + 98304);
    short* Rbf  = (short*)(smem + 114688);
    float* sc   = (float*)(smem + 131072);
    int*   tsl  = (int*)(smem + 133120);

    const int tid = threadIdx.x;
    const int bid = blockIdx.x;
    // Per-XCD dynamic tile queue (R6 mechanism, R13 fixes): XCD k (= bid&7)
    // owns tiles [200k,200k+200). Counters are 128B apart (no line sharing);
    // the atomic is ISSUED at convert start and CONSUMED at scores start
    // (~5K cycles later), so the cross-die round trip never stalls a phase.
    // Near-simultaneous pulls get adjacent tiles -> both 64B halves of each
    // 128B HBM line consumed from one L2 fetch (pairing preserved, per R6).
    const int xcd = bid & 7;
    const int w   = __builtin_amdgcn_readfirstlane(tid >> 6); // wave id
    const int l   = tid & 63;
    const int g   = l >> 4;        // k-group within fragment
    const int sl  = l & 15;        // row/col-within-tile lane index
    const int c0  = w * 16;

    const unsigned xfbase = lds_u32(Xf32);
    const unsigned xbase  = lds_u32(Xbf);

    // ---- DMA issue for one tile at spatial offset S (async, no waits) ------
    auto stage_dma = [&](int S) {
        #pragma unroll
        for (int i = 0; i < 8; ++i) {
            int idx = i * 512 + tid;          // [0,4096) float4 slots
            int q  = idx & 3;
            int r  = idx >> 2;
            int cc = r & 127;
            int b  = (r >> 7) & 3;
            int m  = r >> 9;                  // wave-uniform (64-slot spans)
            const float* fp = m ? feat1 : feat0;
            // dest (uniform per wave+i): lane j lands at slot i*512+w*64+j
            dma16(fp + (size_t)((b * 128 + cc) * HW + S + q * 4),
                  xfbase + (unsigned)((i * 512 + (w << 6)) << 4));
        }
    };

    // ---------------- prologue: pull 2 tiles; DMA first; weights ------------
    if (tid == 0) {
        int n0 = atomicAdd(cnt + xcd * 32, 1);
        int n1 = atomicAdd(cnt + xcd * 32, 1);
        tsl[0] = (n0 < TPX) ? (TPX * xcd + n0) : -1;
        tsl[1] = (n1 < TPX) ? (TPX * xcd + n1) : -1;
    }
    bar_lgkm();
    int t_cur = tsl[0];           // always valid: 64 upfront pulls < 200/XCD
    int t_nxt = tsl[1];

    stage_dma(t_cur * TS);

    short8 afc[8];
    #pragma unroll
    for (int ks = 0; ks < 8; ++ks) {
        const int k0 = ks * 32 + g * 8;
        const float4 w0 = *reinterpret_cast<const float4*>(conv_w + (c0 + sl) * 256 + k0);
        const float4 w1 = *reinterpret_cast<const float4*>(conv_w + (c0 + sl) * 256 + k0 + 4);
        const float4 a0 = *reinterpret_cast<const float4*>(adapter + k0);
        const float4 a1 = *reinterpret_cast<const float4*>(adapter + k0 + 4);
        uint4v au;
        au[0] = cvt_pk(w0.x * a0.x, w0.y * a0.y);
        au[1] = cvt_pk(w0.z * a0.z, w0.w * a0.w);
        au[2] = cvt_pk(w1.x * a1.x, w1.y * a1.y);
        au[3] = cvt_pk(w1.z * a1.z, w1.w * a1.w);
        afc[ks] = __builtin_bit_cast(short8, au);
    }
    short8 afm[4];
    #pragma unroll
    for (int ks = 0; ks < 4; ++ks) {
        const int k0 = ks * 32 + g * 8;
        const float4 w0 = *reinterpret_cast<const float4*>(mlp_w + (c0 + sl) * 128 + k0);
        const float4 w1 = *reinterpret_cast<const float4*>(mlp_w + (c0 + sl) * 128 + k0 + 4);
        uint4v au;
        au[0] = cvt_pk(w0.x, w0.y);
        au[1] = cvt_pk(w0.z, w0.w);
        au[2] = cvt_pk(w1.x, w1.y);
        au[3] = cvt_pk(w1.z, w1.w);
        afm[ks] = __builtin_bit_cast(short8, au);
    }
    float bias[4], mb[4];
    #pragma unroll
    for (int i = 0; i < 4; ++i) {
        bias[i] = conv_b[c0 + g * 4 + i];
        mb[i]   = mlp_b[c0 + g * 4 + i];
    }
    wait_vm0();     // DMA(first tile) + weight loads + atomics landed
    bar_lgkm();

    for (;;) {
        const int S = t_cur * TS;

        // ---- queue pull for tile i+2: ISSUE only (result consumed at scores
        // start, ~5K cycles later -> cross-die latency fully hidden).
        int nv = TPX;
        if (tid == 0) nv = atomicAdd(cnt + xcd * 32, 1);

        // ---- phase 1: convert Xf32 -> Xbf[b][m*128+cc][s] bf16 (LDS->LDS) --
        // No barrier precedes this on loop re-entry (R12): convert touches
        // only Xbf (dead since scores) and this wave's OWN Xf32 slots.
        #pragma unroll
        for (int i = 0; i < 8; ++i) {
            int idx = i * 512 + tid;
            const float4 v = *reinterpret_cast<const float4*>(Xf32 + (size_t)idx * 4);
            int q  = idx & 3;
            int r  = idx >> 2;
            int cc = r & 127;
            int b  = (r >> 7) & 3;
            int m  = r >> 9;
            uint2v xv;
            xv[0] = cvt_pk(v.x, v.y);
            xv[1] = cvt_pk(v.z, v.w);
            *reinterpret_cast<uint2v*>(Xbf + b * 4096 + (m * 128 + cc) * 16 + q * 4) = xv;
        }
        bar_lgkm();   // Xbf visible; Xf32 free (all waves' reads drained)

        // ---- issue DMA for next tile (lands under the 4 compute phases) ----
        if (t_nxt >= 0) stage_dma(t_nxt * TS);

        // ---------------- conv via MFMA, 2-deep pipelined tr clusters --------
        {
            f32x4 acc[4] = {{0,0,0,0},{0,0,0,0},{0,0,0,0},{0,0,0,0}};
            Clu cA, cB;
            issue_clu(cA, xbase + 0 * 1024 + g * 256 + sl * 8, 8192);
            #pragma unroll
            for (int ks = 0; ks < 8; ++ks) {
                Clu& cur = (ks & 1) ? cB : cA;
                Clu& nxt = (ks & 1) ? cA : cB;
                if (ks < 7) {
                    issue_clu(nxt, xbase + (ks + 1) * 1024 + g * 256 + sl * 8, 8192);
                    wait_lgkm8();
                } else {
                    wait_lgkm0();
                }
                acc[0] = __builtin_amdgcn_mfma_f32_16x16x32_bf16(afc[ks], mk8(cur.lo0, cur.hi0), acc[0], 0, 0, 0);
                acc[1] = __builtin_amdgcn_mfma_f32_16x16x32_bf16(afc[ks], mk8(cur.lo1, cur.hi1), acc[1], 0, 0, 0);
                acc[2] = __builtin_amdgcn_mfma_f32_16x16x32_bf16(afc[ks], mk8(cur.lo2, cur.hi2), acc[2], 0, 0, 0);
                acc[3] = __builtin_amdgcn_mfma_f32_16x16x32_bf16(afc[ks], mk8(cur.lo3, cur.hi3), acc[3], 0, 0, 0);
            }
            #pragma unroll
            for (int tt = 0; tt < 4; ++tt) {
                const int col = tt * 16 + sl;
                uint2v fu;
                fu[0] = cvt_pk(acc[tt][0] + bias[0], acc[tt][1] + bias[1]);
                fu[1] = cvt_pk(acc[tt][2] + bias[2], acc[tt][3] + bias[3]);
                *reinterpret_cast<uint2v*>(fbf + col * 128 + (((c0 + g * 4) ^ (sl << 3)) ^ (tt << 5))) = fu;
            }
        }
        bar_lgkm();

        // -------- scores via MFMA + in-register softmax ----------------------
        {
            // consume the queue pull (atomic issued pre-convert: landed)
            if (tid == 0) tsl[2] = (nv < TPX) ? (TPX * xcd + nv) : -1;
            const int sm_m = w >> 2;
            const int sm_b = w & 3;
            const int ad = sl >> 2;
            const int aq = sl & 3;
            const unsigned fbase = lds_u32(fbf);
            const unsigned btile = xbase + sm_b * 8192 + sm_m * 4096 + g * 256 + sl * 8;
            f32x4 accS[4] = {{0,0,0,0},{0,0,0,0},{0,0,0,0},{0,0,0,0}};
            struct SC { short4v blo, bhi; uint4v a0, a1, a2, a3; };
            SC pA, pB;
            auto issue = [&](SC& Sv, int kk) {
                const unsigned bt = btile + (unsigned)(kk * 1024);
                Sv.blo = tr_read(bt); Sv.bhi = tr_read128(bt);
                const int cg = kk * 4 + g;
                Sv.a0 = lds_b128(fbase + (unsigned)((ad * 16 + 0 + aq) * 256 + (((cg ^ (0 + aq)) ^ (ad << 2)) << 4)));
                Sv.a1 = lds_b128(fbase + (unsigned)((ad * 16 + 4 + aq) * 256 + (((cg ^ (4 + aq)) ^ (ad << 2)) << 4)));
                Sv.a2 = lds_b128(fbase + (unsigned)((ad * 16 + 8 + aq) * 256 + (((cg ^ (8 + aq)) ^ (ad << 2)) << 4)));
                Sv.a3 = lds_b128(fbase + (unsigned)((ad * 16 + 12 + aq) * 256 + (((cg ^ (12 + aq)) ^ (ad << 2)) << 4)));
            };
            issue(pA, 0);
            #pragma unroll
            for (int kk = 0; kk < 4; ++kk) {
                SC& cur = (kk & 1) ? pB : pA;
                SC& nxt = (kk & 1) ? pA : pB;
                if (kk < 3) {
                    issue(nxt, kk + 1);
                    wait_lgkm6();
                } else {
                    wait_lgkm0();
                }
                const short8 bf = mk8(cur.blo, cur.bhi);
                accS[0] = __builtin_amdgcn_mfma_f32_16x16x32_bf16(__builtin_bit_cast(short8, cur.a0), bf, accS[0], 0, 0, 0);
                accS[1] = __builtin_amdgcn_mfma_f32_16x16x32_bf16(__builtin_bit_cast(short8, cur.a1), bf, accS[1], 0, 0, 0);
                accS[2] = __builtin_amdgcn_mfma_f32_16x16x32_bf16(__builtin_bit_cast(short8, cur.a2), bf, accS[2], 0, 0, 0);
                accS[3] = __builtin_amdgcn_mfma_f32_16x16x32_bf16(__builtin_bit_cast(short8, cur.a3), bf, accS[3], 0, 0, 0);
            }
            const int cstar = sl >> 2, qstar = sl & 3;
            float x = accS[0][0];
            #pragma unroll
            for (int c = 0; c < 4; ++c)
                #pragma unroll
                for (int q = 0; q < 4; ++q)
                    if (c == cstar && q == qstar) x = accS[c][q];
            x *= 0.088388347648318447f;   // 1/sqrt(128)
            float mx = fmaxf(x, __shfl_xor(x, 16));
            mx = fmaxf(mx, __shfl_xor(mx, 32));
            float e = __expf(x - mx);
            float sm = e + __shfl_xor(e, 16);
            sm += __shfl_xor(sm, 32);
            sc[(sm_m * 16 + sm_b * 4 + g) * 16 + sl] = e / sm;
        }
        bar_lgkm();   // scores + tsl[2] visible to all waves

        // ---------------- retrieved[col][cc] = sum_d aw[d]*f[(d,s)][cc] -----
        {
            const int b = l >> 4, s = l & 15;
            float aw[4];
            #pragma unroll
            for (int d = 0; d < 4; ++d)
                aw[d] = sc[(b * 4 + d) * 16 + s] + sc[(16 + b * 4 + d) * 16 + s];
            #pragma unroll
            for (int h = 0; h < 2; ++h) {
                const int cb = w * 2 + h;
                float r[8] = {0,0,0,0,0,0,0,0};
                #pragma unroll
                for (int d = 0; d < 4; ++d) {
                    const int colf = d * 16 + s;
                    short8 fv = *reinterpret_cast<const short8*>(
                        fbf + colf * 128 + (((cb ^ s) ^ (d << 2)) << 3));
                    #pragma unroll
                    for (int e = 0; e < 8; ++e) r[e] += aw[d] * bf2f(fv[e]);
                }
                #pragma unroll
                for (int e = 0; e < 8; e += 2) {
                    unsigned uu = cvt_pk(r[e], r[e + 1]);
                    Rbf[b * 2048 + (cb * 8 + e) * 16 + s]     = (short)(uu & 0xffffu);
                    Rbf[b * 2048 + (cb * 8 + e + 1) * 16 + s] = (short)(uu >> 16);
                }
            }
        }
        bar_lgkm();

        // ---------------- MLP via MFMA + relu + residual + out ---------------
        {
            f32x4 acc[4] = {{0,0,0,0},{0,0,0,0},{0,0,0,0},{0,0,0,0}};
            const unsigned rbase = lds_u32(Rbf);
            Clu cA, cB;
            issue_clu(cA, rbase + 0 * 1024 + g * 256 + sl * 8, 4096);
            #pragma unroll
            for (int ks = 0; ks < 4; ++ks) {
                Clu& cur = (ks & 1) ? cB : cA;
                Clu& nxt = (ks & 1) ? cA : cB;
                if (ks < 3) {
                    issue_clu(nxt, rbase + (ks + 1) * 1024 + g * 256 + sl * 8, 4096);
                    wait_lgkm8();
                } else {
                    wait_lgkm0();
                }
                acc[0] = __builtin_amdgcn_mfma_f32_16x16x32_bf16(afm[ks], mk8(cur.lo0, cur.hi0), acc[0], 0, 0, 0);
                acc[1] = __builtin_amdgcn_mfma_f32_16x16x32_bf16(afm[ks], mk8(cur.lo1, cur.hi1), acc[1], 0, 0, 0);
                acc[2] = __builtin_amdgcn_mfma_f32_16x16x32_bf16(afm[ks], mk8(cur.lo2, cur.hi2), acc[2], 0, 0, 0);
                acc[3] = __builtin_amdgcn_mfma_f32_16x16x32_bf16(afm[ks], mk8(cur.lo3, cur.hi3), acc[3], 0, 0, 0);
            }
            // Drain the next tile's DMA BEFORE issuing stores: per-wave vmcnt
            // then counts only DMA (stores not yet issued). The stores below
            // run unwaited and overlap the next tile's convert+conv phases.
            wait_vm0();
            #pragma unroll
            for (int tt = 0; tt < 4; ++tt) {
                const int col = tt * 16 + sl;    // b = tt, s = sl
                const short4v res = *reinterpret_cast<const short4v*>(
                    fbf + col * 128 + (((c0 + g * 4) ^ (sl << 3)) ^ (tt << 5)));
                #pragma unroll
                for (int i = 0; i < 4; ++i) {
                    const int c = c0 + g * 4 + i;
                    float v = fmaxf(acc[tt][i] + mb[i], 0.f) + bf2f(res[i]);
                    out[(size_t)(tt * 128 + c) * HW + S + sl] = v;
                }
            }
        }
        // No end-of-tile barrier (R12): next convert touches only Xbf (dead)
        // + this wave's own Xf32 slots (DMA drained by wait_vm0 above).
        // tsl[2] visibility was established at the scores-end barrier; it is
        // not rewritten until after the NEXT conv-end barrier, so this read
        // cannot race with the next write.
        t_cur = t_nxt;
        t_nxt = tsl[2];
        if (t_cur < 0) break;
    }
}

extern "C" void kernel_launch(void* const* d_in, const int* in_sizes, int n_in,
                              void* d_out, int out_size, void* d_ws, size_t ws_size,
                              hipStream_t stream) {
    const float* feat0   = (const float*)d_in[0];
    const float* feat1   = (const float*)d_in[1];
    const float* adapter = (const float*)d_in[2];
    const float* conv_w  = (const float*)d_in[3];
    const float* conv_b  = (const float*)d_in[4];
    const float* mlp_w   = (const float*)d_in[5];
    const float* mlp_b   = (const float*)d_in[6];
    float* out = (float*)d_out;
    int* cnt = (int*)d_ws;

    // zero the 8 per-XCD tile counters (128B apart -> no line sharing)
    hipMemsetAsync(d_ws, 0, 1024, stream);

    dim3 grid(NB);     // 256 persistent blocks, dynamic per-XCD tile queues
    dim3 block(512);
    hipLaunchKernelGGL(mmf_kernel, grid, block, 0, stream,
                       feat0, feat1, adapter, conv_w, conv_b, mlp_w, mlp_b, out, cnt);
}

// Round 14
// 48.709 us; speedup vs baseline: 1.0985x; 1.0985x over previous
//
#include <hip/hip_runtime.h>

#define HW 25600
#define TS 16   // spatial locations per tile
#define NT 1600 // total tiles
#define NB 256  // persistent blocks (1 per CU; LDS forces 1 block/CU)

typedef float  f32x4   __attribute__((ext_vector_type(4)));
typedef short  short8  __attribute__((ext_vector_type(8)));
typedef short  short4v __attribute__((ext_vector_type(4)));
typedef unsigned int uint2v __attribute__((ext_vector_type(2)));
typedef unsigned int uint4v __attribute__((ext_vector_type(4)));

__device__ __forceinline__ float bf2f(short h) {
    return __builtin_bit_cast(float, (unsigned)((unsigned short)h) << 16);
}
// HW packed f32->bf16 (RNE): D.lo = bf16(a), D.hi = bf16(b)
__device__ __forceinline__ unsigned cvt_pk(float a, float b) {
    unsigned r;
    asm("v_cvt_pk_bf16_f32 %0, %1, %2" : "=v"(r) : "v"(a), "v"(b));
    return r;
}

typedef __attribute__((address_space(3))) const char lds_cchar;
typedef __attribute__((address_space(3))) char lds_char;
typedef __attribute__((address_space(1))) const void g_cvoid;
__device__ __forceinline__ unsigned lds_u32(const void* p) {
    return (unsigned)(uintptr_t)(lds_cchar*)p;
}
// Async global->LDS DMA, 16B/lane. Dest = lds_base + lane*16 (linear);
// global source address is per-lane. No VGPR destination => no spill pressure.
__device__ __forceinline__ void dma16(const float* g, unsigned lds_byte) {
    __builtin_amdgcn_global_load_lds(
        (g_cvoid*)g,
        (__attribute__((address_space(3))) void*)(lds_char*)(uintptr_t)lds_byte,
        16, 0, 0);
}

// ds_read_b64_tr_b16: lane addr = tile_base(128B-aligned) + lane16*8.
// Elem j = bf16 at tile_base + lane16*2 + j*32. offset:128 -> next 4 rows.
__device__ __forceinline__ short4v tr_read(unsigned a) {
    short4v d;
    asm volatile("ds_read_b64_tr_b16 %0, %1" : "=v"(d) : "v"(a) : "memory");
    return d;
}
__device__ __forceinline__ short4v tr_read128(unsigned a) {
    short4v d;
    asm volatile("ds_read_b64_tr_b16 %0, %1 offset:128" : "=v"(d) : "v"(a) : "memory");
    return d;
}
__device__ __forceinline__ uint4v lds_b128(unsigned a) {
    uint4v d;
    asm volatile("ds_read_b128 %0, %1" : "=v"(d) : "v"(a) : "memory");
    return d;
}
// Counted lgkm waits for the 2-deep DS pipelines (rule #18: SB(0) after).
__device__ __forceinline__ void wait_lgkm8() {
    asm volatile("s_waitcnt lgkmcnt(8)" ::: "memory");
    __builtin_amdgcn_sched_barrier(0);
}
__device__ __forceinline__ void wait_lgkm6() {
    asm volatile("s_waitcnt lgkmcnt(6)" ::: "memory");
    __builtin_amdgcn_sched_barrier(0);
}
__device__ __forceinline__ void wait_lgkm4() {
    asm volatile("s_waitcnt lgkmcnt(4)" ::: "memory");
    __builtin_amdgcn_sched_barrier(0);
}
__device__ __forceinline__ void wait_lgkm0() {
    asm volatile("s_waitcnt lgkmcnt(0)" ::: "memory");
    __builtin_amdgcn_sched_barrier(0);
}
__device__ __forceinline__ void wait_vm0() {
    asm volatile("s_waitcnt vmcnt(0)" ::: "memory");
    __builtin_amdgcn_sched_barrier(0);
}
// Barrier that drains only LDS ops; VMEM (DMA, stores) stays in flight.
__device__ __forceinline__ void bar_lgkm() {
    asm volatile("s_waitcnt lgkmcnt(0)" ::: "memory");
    __builtin_amdgcn_s_barrier();
    asm volatile("" ::: "memory");
}

// 8-read tr cluster: 4 tiles (t=0..3) x (lo, hi)
struct Clu { short4v lo0, hi0, lo1, hi1, lo2, hi2, lo3, hi3; };
__device__ __forceinline__ void issue_clu(Clu& C, unsigned base, int tstride) {
    C.lo0 = tr_read(base);                C.hi0 = tr_read128(base);
    C.lo1 = tr_read(base + tstride);      C.hi1 = tr_read128(base + tstride);
    C.lo2 = tr_read(base + 2 * tstride);  C.hi2 = tr_read128(base + 2 * tstride);
    C.lo3 = tr_read(base + 3 * tstride);  C.hi3 = tr_read128(base + 3 * tstride);
}
__device__ __forceinline__ short8 mk8(short4v lo, short4v hi) {
    return __builtin_shufflevector(lo, hi, 0, 1, 2, 3, 4, 5, 6, 7);
}

// LDS layout (bytes), 133120 total (1 block/CU):
//  Xf32 [4096] float4      0      .. 65536   DMA landing buffer (f32, linear)
//  Xbf  [4][256][16] bf16   65536  .. 98304   feats (b-major), bf16
//  fbf  [64][128]   bf16    98304  .. 114688  f (conv out), swizzle c^(s<<3)^(t<<5)
//  Rbf  [4][16][128] bf16   114688 .. 131072  retrieved, [b][s][c] with c-block
//       swizzle v = cblk ^ s ^ (b<<2): retrieved writes ONE b128/thread,
//       MLP reads ONE b128/fragment, both minimal-bank (R14 change).
//  sc   [32][16]    f32     131072 .. 133120  attn weights
__global__ __launch_bounds__(512, 2) void mmf_kernel(
    const float* __restrict__ feat0, const float* __restrict__ feat1,
    const float* __restrict__ adapter, const float* __restrict__ conv_w,
    const float* __restrict__ conv_b, const float* __restrict__ mlp_w,
    const float* __restrict__ mlp_b, float* __restrict__ out)
{
    __shared__ __align__(128) char smem[133120];
    float* Xf32 = (float*)smem;
    short* Xbf  = (short*)(smem + 65536);
    short* fbf  = (short*)(smem + 98304);
    short* Rbf  = (short*)(smem + 114688);
    float* sc   = (float*)(smem + 131072);

    const int tid = threadIdx.x;
    const int bid = blockIdx.x;
    // XCD-region striping (R5): XCD k (= bid&7) owns tiles [200k, 200k+200);
    // its 32 blocks stride by 32. Adjacent tiles run on adjacent blocks of the
    // SAME XCD concurrently -> both 64B halves of each 128B HBM line are
    // consumed from one L2 fetch.
    const int xcd  = bid & 7;
    const int jb   = bid >> 3;             // 0..31 within XCD
    const int tbeg = 200 * xcd + jb;
    const int tend = 200 * (xcd + 1);
    const int w   = __builtin_amdgcn_readfirstlane(tid >> 6); // wave id
    const int l   = tid & 63;
    const int g   = l >> 4;        // k-group within fragment
    const int sl  = l & 15;        // row/col-within-tile lane index
    const int c0  = w * 16;

    const unsigned xfbase = lds_u32(Xf32);
    const unsigned xbase  = lds_u32(Xbf);
    const unsigned rbase  = lds_u32(Rbf);

    // ---- DMA issue for one tile at spatial offset S (async, no waits) ------
    auto stage_dma = [&](int S) {
        #pragma unroll
        for (int i = 0; i < 8; ++i) {
            int idx = i * 512 + tid;          // [0,4096) float4 slots
            int q  = idx & 3;
            int r  = idx >> 2;
            int cc = r & 127;
            int b  = (r >> 7) & 3;
            int m  = r >> 9;                  // wave-uniform (64-slot spans)
            const float* fp = m ? feat1 : feat0;
            // dest (uniform per wave+i): lane j lands at slot i*512+w*64+j
            dma16(fp + (size_t)((b * 128 + cc) * HW + S + q * 4),
                  xfbase + (unsigned)((i * 512 + (w << 6)) << 4));
        }
    };

    // ---------------- prologue: DMA first tile; build weight fragments ------
    stage_dma(tbeg * TS);

    short8 afc[8];
    #pragma unroll
    for (int ks = 0; ks < 8; ++ks) {
        const int k0 = ks * 32 + g * 8;
        const float4 w0 = *reinterpret_cast<const float4*>(conv_w + (c0 + sl) * 256 + k0);
        const float4 w1 = *reinterpret_cast<const float4*>(conv_w + (c0 + sl) * 256 + k0 + 4);
        const float4 a0 = *reinterpret_cast<const float4*>(adapter + k0);
        const float4 a1 = *reinterpret_cast<const float4*>(adapter + k0 + 4);
        uint4v au;
        au[0] = cvt_pk(w0.x * a0.x, w0.y * a0.y);
        au[1] = cvt_pk(w0.z * a0.z, w0.w * a0.w);
        au[2] = cvt_pk(w1.x * a1.x, w1.y * a1.y);
        au[3] = cvt_pk(w1.z * a1.z, w1.w * a1.w);
        afc[ks] = __builtin_bit_cast(short8, au);
    }
    short8 afm[4];
    #pragma unroll
    for (int ks = 0; ks < 4; ++ks) {
        const int k0 = ks * 32 + g * 8;
        const float4 w0 = *reinterpret_cast<const float4*>(mlp_w + (c0 + sl) * 128 + k0);
        const float4 w1 = *reinterpret_cast<const float4*>(mlp_w + (c0 + sl) * 128 + k0 + 4);
        uint4v au;
        au[0] = cvt_pk(w0.x, w0.y);
        au[1] = cvt_pk(w0.z, w0.w);
        au[2] = cvt_pk(w1.x, w1.y);
        au[3] = cvt_pk(w1.z, w1.w);
        afm[ks] = __builtin_bit_cast(short8, au);
    }
    float bias[4], mb[4];
    #pragma unroll
    for (int i = 0; i < 4; ++i) {
        bias[i] = conv_b[c0 + g * 4 + i];
        mb[i]   = mlp_b[c0 + g * 4 + i];
    }
    wait_vm0();     // DMA(first tile) + weight loads landed
    bar_lgkm();

    for (int ti = tbeg; ti < tend; ti += 32) {
        const int S = ti * TS;

        // ---- phase 1: convert Xf32 -> Xbf[b][m*128+cc][s] bf16 (LDS->LDS) --
        // No barrier precedes this on loop re-entry (R12): convert touches
        // only Xbf (dead since scores) and this wave's OWN Xf32 slots.
        #pragma unroll
        for (int i = 0; i < 8; ++i) {
            int idx = i * 512 + tid;
            const float4 v = *reinterpret_cast<const float4*>(Xf32 + (size_t)idx * 4);
            int q  = idx & 3;
            int r  = idx >> 2;
            int cc = r & 127;
            int b  = (r >> 7) & 3;
            int m  = r >> 9;
            uint2v xv;
            xv[0] = cvt_pk(v.x, v.y);
            xv[1] = cvt_pk(v.z, v.w);
            *reinterpret_cast<uint2v*>(Xbf + b * 4096 + (m * 128 + cc) * 16 + q * 4) = xv;
        }
        bar_lgkm();   // Xbf visible; Xf32 free (all waves' reads drained)

        // ---- issue DMA for next tile (lands under the 4 compute phases) ----
        if (ti + 32 < tend) stage_dma((ti + 32) * TS);

        // ---------------- conv via MFMA, 2-deep pipelined tr clusters --------
        {
            f32x4 acc[4] = {{0,0,0,0},{0,0,0,0},{0,0,0,0},{0,0,0,0}};
            Clu cA, cB;
            issue_clu(cA, xbase + 0 * 1024 + g * 256 + sl * 8, 8192);
            #pragma unroll
            for (int ks = 0; ks < 8; ++ks) {
                Clu& cur = (ks & 1) ? cB : cA;
                Clu& nxt = (ks & 1) ? cA : cB;
                if (ks < 7) {
                    issue_clu(nxt, xbase + (ks + 1) * 1024 + g * 256 + sl * 8, 8192);
                    wait_lgkm8();
                } else {
                    wait_lgkm0();
                }
                acc[0] = __builtin_amdgcn_mfma_f32_16x16x32_bf16(afc[ks], mk8(cur.lo0, cur.hi0), acc[0], 0, 0, 0);
                acc[1] = __builtin_amdgcn_mfma_f32_16x16x32_bf16(afc[ks], mk8(cur.lo1, cur.hi1), acc[1], 0, 0, 0);
                acc[2] = __builtin_amdgcn_mfma_f32_16x16x32_bf16(afc[ks], mk8(cur.lo2, cur.hi2), acc[2], 0, 0, 0);
                acc[3] = __builtin_amdgcn_mfma_f32_16x16x32_bf16(afc[ks], mk8(cur.lo3, cur.hi3), acc[3], 0, 0, 0);
            }
            #pragma unroll
            for (int tt = 0; tt < 4; ++tt) {
                const int col = tt * 16 + sl;
                uint2v fu;
                fu[0] = cvt_pk(acc[tt][0] + bias[0], acc[tt][1] + bias[1]);
                fu[1] = cvt_pk(acc[tt][2] + bias[2], acc[tt][3] + bias[3]);
                *reinterpret_cast<uint2v*>(fbf + col * 128 + (((c0 + g * 4) ^ (sl << 3)) ^ (tt << 5))) = fu;
            }
        }
        bar_lgkm();

        // -------- scores via MFMA + in-register softmax ----------------------
        {
            const int sm_m = w >> 2;
            const int sm_b = w & 3;
            const int ad = sl >> 2;
            const int aq = sl & 3;
            const unsigned fbase = lds_u32(fbf);
            const unsigned btile = xbase + sm_b * 8192 + sm_m * 4096 + g * 256 + sl * 8;
            f32x4 accS[4] = {{0,0,0,0},{0,0,0,0},{0,0,0,0},{0,0,0,0}};
            struct SC { short4v blo, bhi; uint4v a0, a1, a2, a3; };
            SC pA, pB;
            auto issue = [&](SC& Sv, int kk) {
                const unsigned bt = btile + (unsigned)(kk * 1024);
                Sv.blo = tr_read(bt); Sv.bhi = tr_read128(bt);
                const int cg = kk * 4 + g;
                Sv.a0 = lds_b128(fbase + (unsigned)((ad * 16 + 0 + aq) * 256 + (((cg ^ (0 + aq)) ^ (ad << 2)) << 4)));
                Sv.a1 = lds_b128(fbase + (unsigned)((ad * 16 + 4 + aq) * 256 + (((cg ^ (4 + aq)) ^ (ad << 2)) << 4)));
                Sv.a2 = lds_b128(fbase + (unsigned)((ad * 16 + 8 + aq) * 256 + (((cg ^ (8 + aq)) ^ (ad << 2)) << 4)));
                Sv.a3 = lds_b128(fbase + (unsigned)((ad * 16 + 12 + aq) * 256 + (((cg ^ (12 + aq)) ^ (ad << 2)) << 4)));
            };
            issue(pA, 0);
            #pragma unroll
            for (int kk = 0; kk < 4; ++kk) {
                SC& cur = (kk & 1) ? pB : pA;
                SC& nxt = (kk & 1) ? pA : pB;
                if (kk < 3) {
                    issue(nxt, kk + 1);
                    wait_lgkm6();
                } else {
                    wait_lgkm0();
                }
                const short8 bf = mk8(cur.blo, cur.bhi);
                accS[0] = __builtin_amdgcn_mfma_f32_16x16x32_bf16(__builtin_bit_cast(short8, cur.a0), bf, accS[0], 0, 0, 0);
                accS[1] = __builtin_amdgcn_mfma_f32_16x16x32_bf16(__builtin_bit_cast(short8, cur.a1), bf, accS[1], 0, 0, 0);
                accS[2] = __builtin_amdgcn_mfma_f32_16x16x32_bf16(__builtin_bit_cast(short8, cur.a2), bf, accS[2], 0, 0, 0);
                accS[3] = __builtin_amdgcn_mfma_f32_16x16x32_bf16(__builtin_bit_cast(short8, cur.a3), bf, accS[3], 0, 0, 0);
            }
            const int cstar = sl >> 2, qstar = sl & 3;
            float x = accS[0][0];
            #pragma unroll
            for (int c = 0; c < 4; ++c)
                #pragma unroll
                for (int q = 0; q < 4; ++q)
                    if (c == cstar && q == qstar) x = accS[c][q];
            x *= 0.088388347648318447f;   // 1/sqrt(128)
            float mx = fmaxf(x, __shfl_xor(x, 16));
            mx = fmaxf(mx, __shfl_xor(mx, 32));
            float e = __expf(x - mx);
            float sm = e + __shfl_xor(e, 16);
            sm += __shfl_xor(sm, 32);
            sc[(sm_m * 16 + sm_b * 4 + g) * 16 + sl] = e / sm;
        }
        bar_lgkm();

        // ---- retrieved[b][s][c] = sum_d aw[d]*f[(d,s)][c], b128 writes -----
        {
            const int b = l >> 4, s = l & 15;
            float aw[4];
            #pragma unroll
            for (int d = 0; d < 4; ++d)
                aw[d] = sc[(b * 4 + d) * 16 + s] + sc[(16 + b * 4 + d) * 16 + s];
            #pragma unroll
            for (int h = 0; h < 2; ++h) {
                const int cb = w * 2 + h;       // c-block (8 channels)
                float r[8] = {0,0,0,0,0,0,0,0};
                #pragma unroll
                for (int d = 0; d < 4; ++d) {
                    const int colf = d * 16 + s;
                    short8 fv = *reinterpret_cast<const short8*>(
                        fbf + colf * 128 + (((cb ^ s) ^ (d << 2)) << 3));
                    #pragma unroll
                    for (int e = 0; e < 8; ++e) r[e] += aw[d] * bf2f(fv[e]);
                }
                // one swizzled b128 store: [b][s][(cb ^ s ^ (b<<2))*8 ..]
                uint4v rv;
                rv[0] = cvt_pk(r[0], r[1]);
                rv[1] = cvt_pk(r[2], r[3]);
                rv[2] = cvt_pk(r[4], r[5]);
                rv[3] = cvt_pk(r[6], r[7]);
                const int v = ((cb ^ s) ^ (b << 2)) & 15;
                *reinterpret_cast<uint4v*>(Rbf + b * 2048 + s * 128 + v * 8) = rv;
            }
        }
        bar_lgkm();

        // ---------------- MLP via MFMA (b128 frags) + relu + residual + out -
        {
            f32x4 acc[4] = {{0,0,0,0},{0,0,0,0},{0,0,0,0},{0,0,0,0}};
            // B-frag for acc[tt], step ks: lane (g,sl) reads 8 consecutive c
            // (k = ks*32+g*8 .. +7) at [tt][sl][v*8], v = (ks*4+g)^sl^(tt<<2).
            struct Qu { uint4v q0, q1, q2, q3; };
            Qu qA, qB;
            auto issue_q = [&](Qu& Q, int ks) {
                const unsigned rb = rbase + (unsigned)(sl * 256);
                const int cb = ks * 4 + g;
                Q.q0 = lds_b128(rb + 0 * 4096 + (unsigned)(((cb ^ sl ^ 0) & 15) << 4));
                Q.q1 = lds_b128(rb + 1 * 4096 + (unsigned)(((cb ^ sl ^ 4) & 15) << 4));
                Q.q2 = lds_b128(rb + 2 * 4096 + (unsigned)(((cb ^ sl ^ 8) & 15) << 4));
                Q.q3 = lds_b128(rb + 3 * 4096 + (unsigned)(((cb ^ sl ^ 12) & 15) << 4));
            };
            issue_q(qA, 0);
            #pragma unroll
            for (int ks = 0; ks < 4; ++ks) {
                Qu& cur = (ks & 1) ? qB : qA;
                Qu& nxt = (ks & 1) ? qA : qB;
                if (ks < 3) {
                    issue_q(nxt, ks + 1);
                    wait_lgkm4();
                } else {
                    wait_lgkm0();
                }
                acc[0] = __builtin_amdgcn_mfma_f32_16x16x32_bf16(afm[ks], __builtin_bit_cast(short8, cur.q0), acc[0], 0, 0, 0);
                acc[1] = __builtin_amdgcn_mfma_f32_16x16x32_bf16(afm[ks], __builtin_bit_cast(short8, cur.q1), acc[1], 0, 0, 0);
                acc[2] = __builtin_amdgcn_mfma_f32_16x16x32_bf16(afm[ks], __builtin_bit_cast(short8, cur.q2), acc[2], 0, 0, 0);
                acc[3] = __builtin_amdgcn_mfma_f32_16x16x32_bf16(afm[ks], __builtin_bit_cast(short8, cur.q3), acc[3], 0, 0, 0);
            }
            // Drain the next tile's DMA BEFORE issuing stores: per-wave vmcnt
            // then counts only DMA (stores not yet issued). The stores below
            // run unwaited and overlap the next tile's convert+conv phases.
            wait_vm0();
            #pragma unroll
            for (int tt = 0; tt < 4; ++tt) {
                const int col = tt * 16 + sl;    // b = tt, s = sl
                const short4v res = *reinterpret_cast<const short4v*>(
                    fbf + col * 128 + (((c0 + g * 4) ^ (sl << 3)) ^ (tt << 5)));
                #pragma unroll
                for (int i = 0; i < 4; ++i) {
                    const int c = c0 + g * 4 + i;
                    float v = fmaxf(acc[tt][i] + mb[i], 0.f) + bf2f(res[i]);
                    out[(size_t)(tt * 128 + c) * HW + S + sl] = v;
                }
            }
        }
        // No end-of-tile barrier (R12): next convert touches only Xbf (dead)
        // + this wave's own Xf32 slots (DMA drained by wait_vm0 above).
    }
}

extern "C" void kernel_launch(void* const* d_in, const int* in_sizes, int n_in,
                              void* d_out, int out_size, void* d_ws, size_t ws_size,
                              hipStream_t stream) {
    const float* feat0   = (const float*)d_in[0];
    const float* feat1   = (const float*)d_in[1];
    const float* adapter = (const float*)d_in[2];
    const float* conv_w  = (const float*)d_in[3];
    const float* conv_b  = (const float*)d_in[4];
    const float* mlp_w   = (const float*)d_in[5];
    const float* mlp_b   = (const float*)d_in[6];
    float* out = (float*)d_out;

    dim3 grid(NB);     // 256 persistent blocks, 6-7 tiles each (XCD-striped)
    dim3 block(512);
    hipLaunchKernelGGL(mmf_kernel, grid, block, 0, stream,
                       feat0, feat1, adapter, conv_w, conv_b, mlp_w, mlp_b, out);
}

// Round 15
// 44.734 us; speedup vs baseline: 1.1961x; 1.0889x over previous
//
#include <hip/hip_runtime.h>

#define HW 25600
#define TS 16   // spatial locations per tile
#define NT 1600 // total tiles
#define NB 256  // persistent blocks (1 per CU; LDS forces 1 block/CU)

typedef float  f32x4   __attribute__((ext_vector_type(4)));
typedef short  short8  __attribute__((ext_vector_type(8)));
typedef short  short4v __attribute__((ext_vector_type(4)));
typedef unsigned int uint2v __attribute__((ext_vector_type(2)));
typedef unsigned int uint4v __attribute__((ext_vector_type(4)));

__device__ __forceinline__ float bf2f(short h) {
    return __builtin_bit_cast(float, (unsigned)((unsigned short)h) << 16);
}
// HW packed f32->bf16 (RNE): D.lo = bf16(a), D.hi = bf16(b)
__device__ __forceinline__ unsigned cvt_pk(float a, float b) {
    unsigned r;
    asm("v_cvt_pk_bf16_f32 %0, %1, %2" : "=v"(r) : "v"(a), "v"(b));
    return r;
}

typedef __attribute__((address_space(3))) const char lds_cchar;
typedef __attribute__((address_space(3))) char lds_char;
typedef __attribute__((address_space(1))) const void g_cvoid;
__device__ __forceinline__ unsigned lds_u32(const void* p) {
    return (unsigned)(uintptr_t)(lds_cchar*)p;
}
// Async global->LDS DMA, 16B/lane. Dest = lds_base + lane*16 (linear);
// global source address is per-lane. No VGPR destination => no spill pressure.
__device__ __forceinline__ void dma16(const float* g, unsigned lds_byte) {
    __builtin_amdgcn_global_load_lds(
        (g_cvoid*)g,
        (__attribute__((address_space(3))) void*)(lds_char*)(uintptr_t)lds_byte,
        16, 0, 0);
}

// ds_read_b64_tr_b16: lane addr = tile_base(128B-aligned) + lane16*8.
// Elem j = bf16 at tile_base + lane16*2 + j*32. offset:128 -> next 4 rows.
__device__ __forceinline__ short4v tr_read(unsigned a) {
    short4v d;
    asm volatile("ds_read_b64_tr_b16 %0, %1" : "=v"(d) : "v"(a) : "memory");
    return d;
}
__device__ __forceinline__ short4v tr_read128(unsigned a) {
    short4v d;
    asm volatile("ds_read_b64_tr_b16 %0, %1 offset:128" : "=v"(d) : "v"(a) : "memory");
    return d;
}
__device__ __forceinline__ uint4v lds_b128(unsigned a) {
    uint4v d;
    asm volatile("ds_read_b128 %0, %1" : "=v"(d) : "v"(a) : "memory");
    return d;
}
// Counted lgkm waits for the 2-deep DS pipelines (rule #18: SB(0) after).
__device__ __forceinline__ void wait_lgkm8() {
    asm volatile("s_waitcnt lgkmcnt(8)" ::: "memory");
    __builtin_amdgcn_sched_barrier(0);
}
__device__ __forceinline__ void wait_lgkm6() {
    asm volatile("s_waitcnt lgkmcnt(6)" ::: "memory");
    __builtin_amdgcn_sched_barrier(0);
}
__device__ __forceinline__ void wait_lgkm4() {
    asm volatile("s_waitcnt lgkmcnt(4)" ::: "memory");
    __builtin_amdgcn_sched_barrier(0);
}
__device__ __forceinline__ void wait_lgkm0() {
    asm volatile("s_waitcnt lgkmcnt(0)" ::: "memory");
    __builtin_amdgcn_sched_barrier(0);
}
__device__ __forceinline__ void wait_vm0() {
    asm volatile("s_waitcnt vmcnt(0)" ::: "memory");
    __builtin_amdgcn_sched_barrier(0);
}
// Barrier that drains only LDS ops; VMEM (DMA, stores) stays in flight.
__device__ __forceinline__ void bar_lgkm() {
    asm volatile("s_waitcnt lgkmcnt(0)" ::: "memory");
    __builtin_amdgcn_s_barrier();
    asm volatile("" ::: "memory");
}

// 8-read tr cluster: 4 tiles (t=0..3) x (lo, hi)
struct Clu { short4v lo0, hi0, lo1, hi1, lo2, hi2, lo3, hi3; };
__device__ __forceinline__ void issue_clu(Clu& C, unsigned base, int tstride) {
    C.lo0 = tr_read(base);                C.hi0 = tr_read128(base);
    C.lo1 = tr_read(base + tstride);      C.hi1 = tr_read128(base + tstride);
    C.lo2 = tr_read(base + 2 * tstride);  C.hi2 = tr_read128(base + 2 * tstride);
    C.lo3 = tr_read(base + 3 * tstride);  C.hi3 = tr_read128(base + 3 * tstride);
}
__device__ __forceinline__ short8 mk8(short4v lo, short4v hi) {
    return __builtin_shufflevector(lo, hi, 0, 1, 2, 3, 4, 5, 6, 7);
}

// LDS layout (bytes), 116736 total (1 block/CU):
//  Xf32 [4096] float4      0      .. 65536   DMA landing buffer (f32, linear)
//  Xbf  [4][256][16] bf16   65536  .. 98304   feats (b-major), bf16
//  fbf  [64][128]   bf16    98304  .. 114688  f (conv out), swizzle c^(s<<3)^(t<<5)
//  sc   [32][16]    f32     114688 .. 116736  attn weights
// R15: Rbf + the retrieved phase are GONE. out = relu(sum_d aw*(f@Wm^T)) + f
// (matmul and aw-sum commute), so MLP runs on fbf directly and the aw-weighted
// sum moves to the f32 epilogue. One phase + one barrier + the Rbf round-trip
// removed; G accumulates in f32 (better precision than bf16 R).
__global__ __launch_bounds__(512, 2) void mmf_kernel(
    const float* __restrict__ feat0, const float* __restrict__ feat1,
    const float* __restrict__ adapter, const float* __restrict__ conv_w,
    const float* __restrict__ conv_b, const float* __restrict__ mlp_w,
    const float* __restrict__ mlp_b, float* __restrict__ out)
{
    __shared__ __align__(128) char smem[116736];
    float* Xf32 = (float*)smem;
    short* Xbf  = (short*)(smem + 65536);
    short* fbf  = (short*)(smem + 98304);
    float* sc   = (float*)(smem + 114688);

    const int tid = threadIdx.x;
    const int bid = blockIdx.x;
    // XCD-region striping (R5): XCD k (= bid&7) owns tiles [200k, 200k+200);
    // its 32 blocks stride by 32. Adjacent tiles run on adjacent blocks of the
    // SAME XCD concurrently -> both 64B halves of each 128B HBM line are
    // consumed from one L2 fetch.
    const int xcd  = bid & 7;
    const int jb   = bid >> 3;             // 0..31 within XCD
    const int tbeg = 200 * xcd + jb;
    const int tend = 200 * (xcd + 1);
    const int w   = __builtin_amdgcn_readfirstlane(tid >> 6); // wave id
    const int l   = tid & 63;
    const int g   = l >> 4;        // k-group within fragment
    const int sl  = l & 15;        // row/col-within-tile lane index
    const int c0  = w * 16;

    const unsigned xfbase = lds_u32(Xf32);
    const unsigned xbase  = lds_u32(Xbf);
    const unsigned fbase  = lds_u32(fbf);

    // ---- DMA issue for one tile at spatial offset S (async, no waits) ------
    auto stage_dma = [&](int S) {
        #pragma unroll
        for (int i = 0; i < 8; ++i) {
            int idx = i * 512 + tid;          // [0,4096) float4 slots
            int q  = idx & 3;
            int r  = idx >> 2;
            int cc = r & 127;
            int b  = (r >> 7) & 3;
            int m  = r >> 9;                  // wave-uniform (64-slot spans)
            const float* fp = m ? feat1 : feat0;
            // dest (uniform per wave+i): lane j lands at slot i*512+w*64+j
            dma16(fp + (size_t)((b * 128 + cc) * HW + S + q * 4),
                  xfbase + (unsigned)((i * 512 + (w << 6)) << 4));
        }
    };

    // ---------------- prologue: DMA first tile; build weight fragments ------
    stage_dma(tbeg * TS);

    short8 afc[8];
    #pragma unroll
    for (int ks = 0; ks < 8; ++ks) {
        const int k0 = ks * 32 + g * 8;
        const float4 w0 = *reinterpret_cast<const float4*>(conv_w + (c0 + sl) * 256 + k0);
        const float4 w1 = *reinterpret_cast<const float4*>(conv_w + (c0 + sl) * 256 + k0 + 4);
        const float4 a0 = *reinterpret_cast<const float4*>(adapter + k0);
        const float4 a1 = *reinterpret_cast<const float4*>(adapter + k0 + 4);
        uint4v au;
        au[0] = cvt_pk(w0.x * a0.x, w0.y * a0.y);
        au[1] = cvt_pk(w0.z * a0.z, w0.w * a0.w);
        au[2] = cvt_pk(w1.x * a1.x, w1.y * a1.y);
        au[3] = cvt_pk(w1.z * a1.z, w1.w * a1.w);
        afc[ks] = __builtin_bit_cast(short8, au);
    }
    short8 afm[4];
    #pragma unroll
    for (int ks = 0; ks < 4; ++ks) {
        const int k0 = ks * 32 + g * 8;
        const float4 w0 = *reinterpret_cast<const float4*>(mlp_w + (c0 + sl) * 128 + k0);
        const float4 w1 = *reinterpret_cast<const float4*>(mlp_w + (c0 + sl) * 128 + k0 + 4);
        uint4v au;
        au[0] = cvt_pk(w0.x, w0.y);
        au[1] = cvt_pk(w0.z, w0.w);
        au[2] = cvt_pk(w1.x, w1.y);
        au[3] = cvt_pk(w1.z, w1.w);
        afm[ks] = __builtin_bit_cast(short8, au);
    }
    float bias[4], mb[4];
    #pragma unroll
    for (int i = 0; i < 4; ++i) {
        bias[i] = conv_b[c0 + g * 4 + i];
        mb[i]   = mlp_b[c0 + g * 4 + i];
    }
    wait_vm0();     // DMA(first tile) + weight loads landed
    bar_lgkm();

    for (int ti = tbeg; ti < tend; ti += 32) {
        const int S = ti * TS;

        // ---- phase 1: convert Xf32 -> Xbf[b][m*128+cc][s] bf16 (LDS->LDS) --
        // No barrier precedes this on loop re-entry (R12): convert touches
        // only Xbf (dead since scores) and this wave's OWN Xf32 slots.
        #pragma unroll
        for (int i = 0; i < 8; ++i) {
            int idx = i * 512 + tid;
            const float4 v = *reinterpret_cast<const float4*>(Xf32 + (size_t)idx * 4);
            int q  = idx & 3;
            int r  = idx >> 2;
            int cc = r & 127;
            int b  = (r >> 7) & 3;
            int m  = r >> 9;
            uint2v xv;
            xv[0] = cvt_pk(v.x, v.y);
            xv[1] = cvt_pk(v.z, v.w);
            *reinterpret_cast<uint2v*>(Xbf + b * 4096 + (m * 128 + cc) * 16 + q * 4) = xv;
        }
        bar_lgkm();   // Xbf visible; Xf32 free (all waves' reads drained)

        // ---- issue DMA for next tile (lands under the compute phases) ------
        if (ti + 32 < tend) stage_dma((ti + 32) * TS);

        // ---------------- conv via MFMA, 2-deep pipelined tr clusters --------
        {
            f32x4 acc[4] = {{0,0,0,0},{0,0,0,0},{0,0,0,0},{0,0,0,0}};
            Clu cA, cB;
            issue_clu(cA, xbase + 0 * 1024 + g * 256 + sl * 8, 8192);
            #pragma unroll
            for (int ks = 0; ks < 8; ++ks) {
                Clu& cur = (ks & 1) ? cB : cA;
                Clu& nxt = (ks & 1) ? cA : cB;
                if (ks < 7) {
                    issue_clu(nxt, xbase + (ks + 1) * 1024 + g * 256 + sl * 8, 8192);
                    wait_lgkm8();
                } else {
                    wait_lgkm0();
                }
                acc[0] = __builtin_amdgcn_mfma_f32_16x16x32_bf16(afc[ks], mk8(cur.lo0, cur.hi0), acc[0], 0, 0, 0);
                acc[1] = __builtin_amdgcn_mfma_f32_16x16x32_bf16(afc[ks], mk8(cur.lo1, cur.hi1), acc[1], 0, 0, 0);
                acc[2] = __builtin_amdgcn_mfma_f32_16x16x32_bf16(afc[ks], mk8(cur.lo2, cur.hi2), acc[2], 0, 0, 0);
                acc[3] = __builtin_amdgcn_mfma_f32_16x16x32_bf16(afc[ks], mk8(cur.lo3, cur.hi3), acc[3], 0, 0, 0);
            }
            #pragma unroll
            for (int tt = 0; tt < 4; ++tt) {
                const int col = tt * 16 + sl;
                uint2v fu;
                fu[0] = cvt_pk(acc[tt][0] + bias[0], acc[tt][1] + bias[1]);
                fu[1] = cvt_pk(acc[tt][2] + bias[2], acc[tt][3] + bias[3]);
                *reinterpret_cast<uint2v*>(fbf + col * 128 + (((c0 + g * 4) ^ (sl << 3)) ^ (tt << 5))) = fu;
            }
        }
        bar_lgkm();

        // -------- scores via MFMA + in-register softmax ----------------------
        {
            const int sm_m = w >> 2;
            const int sm_b = w & 3;
            const int ad = sl >> 2;
            const int aq = sl & 3;
            const unsigned btile = xbase + sm_b * 8192 + sm_m * 4096 + g * 256 + sl * 8;
            f32x4 accS[4] = {{0,0,0,0},{0,0,0,0},{0,0,0,0},{0,0,0,0}};
            struct SC { short4v blo, bhi; uint4v a0, a1, a2, a3; };
            SC pA, pB;
            auto issue = [&](SC& Sv, int kk) {
                const unsigned bt = btile + (unsigned)(kk * 1024);
                Sv.blo = tr_read(bt); Sv.bhi = tr_read128(bt);
                const int cg = kk * 4 + g;
                Sv.a0 = lds_b128(fbase + (unsigned)((ad * 16 + 0 + aq) * 256 + (((cg ^ (0 + aq)) ^ (ad << 2)) << 4)));
                Sv.a1 = lds_b128(fbase + (unsigned)((ad * 16 + 4 + aq) * 256 + (((cg ^ (4 + aq)) ^ (ad << 2)) << 4)));
                Sv.a2 = lds_b128(fbase + (unsigned)((ad * 16 + 8 + aq) * 256 + (((cg ^ (8 + aq)) ^ (ad << 2)) << 4)));
                Sv.a3 = lds_b128(fbase + (unsigned)((ad * 16 + 12 + aq) * 256 + (((cg ^ (12 + aq)) ^ (ad << 2)) << 4)));
            };
            issue(pA, 0);
            #pragma unroll
            for (int kk = 0; kk < 4; ++kk) {
                SC& cur = (kk & 1) ? pB : pA;
                SC& nxt = (kk & 1) ? pA : pB;
                if (kk < 3) {
                    issue(nxt, kk + 1);
                    wait_lgkm6();
                } else {
                    wait_lgkm0();
                }
                const short8 bf = mk8(cur.blo, cur.bhi);
                accS[0] = __builtin_amdgcn_mfma_f32_16x16x32_bf16(__builtin_bit_cast(short8, cur.a0), bf, accS[0], 0, 0, 0);
                accS[1] = __builtin_amdgcn_mfma_f32_16x16x32_bf16(__builtin_bit_cast(short8, cur.a1), bf, accS[1], 0, 0, 0);
                accS[2] = __builtin_amdgcn_mfma_f32_16x16x32_bf16(__builtin_bit_cast(short8, cur.a2), bf, accS[2], 0, 0, 0);
                accS[3] = __builtin_amdgcn_mfma_f32_16x16x32_bf16(__builtin_bit_cast(short8, cur.a3), bf, accS[3], 0, 0, 0);
            }
            const int cstar = sl >> 2, qstar = sl & 3;
            float x = accS[0][0];
            #pragma unroll
            for (int c = 0; c < 4; ++c)
                #pragma unroll
                for (int q = 0; q < 4; ++q)
                    if (c == cstar && q == qstar) x = accS[c][q];
            x *= 0.088388347648318447f;   // 1/sqrt(128)
            float mx = fmaxf(x, __shfl_xor(x, 16));
            mx = fmaxf(mx, __shfl_xor(mx, 32));
            float e = __expf(x - mx);
            float sm = e + __shfl_xor(e, 16);
            sm += __shfl_xor(sm, 32);
            sc[(sm_m * 16 + sm_b * 4 + g) * 16 + sl] = e / sm;
        }
        bar_lgkm();

        // ---- fused MLP: G = f @ Wm^T via MFMA on fbf, then aw-weighted ------
        // sum + relu + residual + out. B-frag for acc[dd], step ks: lane
        // (g,sl) reads 8 consecutive c (k = ks*32+g*8..+7) of f column
        // (dd*16+sl) at byte 16*((ks*4+g) ^ sl ^ (dd<<2))  [same swizzle
        // family scores' A-reads use].
        {
            f32x4 acc[4] = {{0,0,0,0},{0,0,0,0},{0,0,0,0},{0,0,0,0}};
            struct Qu { uint4v q0, q1, q2, q3; };
            Qu qA, qB;
            auto issue_q = [&](Qu& Q, int ks) {
                const int cb = ks * 4 + g;
                Q.q0 = lds_b128(fbase + (unsigned)((0 * 16 + sl) * 256 + (((cb ^ sl) ^ 0)  << 4)));
                Q.q1 = lds_b128(fbase + (unsigned)((1 * 16 + sl) * 256 + (((cb ^ sl) ^ 4)  << 4)));
                Q.q2 = lds_b128(fbase + (unsigned)((2 * 16 + sl) * 256 + (((cb ^ sl) ^ 8)  << 4)));
                Q.q3 = lds_b128(fbase + (unsigned)((3 * 16 + sl) * 256 + (((cb ^ sl) ^ 12) << 4)));
            };
            issue_q(qA, 0);
            #pragma unroll
            for (int ks = 0; ks < 4; ++ks) {
                Qu& cur = (ks & 1) ? qB : qA;
                Qu& nxt = (ks & 1) ? qA : qB;
                if (ks < 3) {
                    issue_q(nxt, ks + 1);
                    wait_lgkm4();
                } else {
                    wait_lgkm0();
                }
                acc[0] = __builtin_amdgcn_mfma_f32_16x16x32_bf16(afm[ks], __builtin_bit_cast(short8, cur.q0), acc[0], 0, 0, 0);
                acc[1] = __builtin_amdgcn_mfma_f32_16x16x32_bf16(afm[ks], __builtin_bit_cast(short8, cur.q1), acc[1], 0, 0, 0);
                acc[2] = __builtin_amdgcn_mfma_f32_16x16x32_bf16(afm[ks], __builtin_bit_cast(short8, cur.q2), acc[2], 0, 0, 0);
                acc[3] = __builtin_amdgcn_mfma_f32_16x16x32_bf16(afm[ks], __builtin_bit_cast(short8, cur.q3), acc[3], 0, 0, 0);
            }
            // acc[dd][i] = G[c0+g*4+i][col = dd*16+sl]
            // aw[b][d] (both m summed) for this lane's s = sl
            float aw_[4][4];
            #pragma unroll
            for (int b = 0; b < 4; ++b)
                #pragma unroll
                for (int d = 0; d < 4; ++d)
                    aw_[b][d] = sc[(b * 4 + d) * 16 + sl] + sc[256 + (b * 4 + d) * 16 + sl];
            // Drain the next tile's DMA BEFORE issuing stores: per-wave vmcnt
            // then counts only DMA (stores not yet issued). The stores below
            // run unwaited and overlap the next tile's convert+conv phases.
            wait_vm0();
            #pragma unroll
            for (int b = 0; b < 4; ++b) {
                const int col = b * 16 + sl;
                const short4v res = *reinterpret_cast<const short4v*>(
                    fbf + col * 128 + (((c0 + g * 4) ^ (sl << 3)) ^ (b << 5)));
                #pragma unroll
                for (int i = 0; i < 4; ++i) {
                    float v = mb[i];
                    #pragma unroll
                    for (int d = 0; d < 4; ++d) v += aw_[b][d] * acc[d][i];
                    const int c = c0 + g * 4 + i;
                    out[(size_t)(b * 128 + c) * HW + S + sl] =
                        fmaxf(v, 0.f) + bf2f(res[i]);
                }
            }
        }
        // No end-of-tile barrier (R12): next convert touches only Xbf (dead)
        // + this wave's own Xf32 slots (DMA drained by wait_vm0 above). fbf/sc
        // are next WRITTEN only after the convert-end (resp. conv-end)
        // barrier, which no wave passes until all waves' reads here drained.
    }
}

extern "C" void kernel_launch(void* const* d_in, const int* in_sizes, int n_in,
                              void* d_out, int out_size, void* d_ws, size_t ws_size,
                              hipStream_t stream) {
    const float* feat0   = (const float*)d_in[0];
    const float* feat1   = (const float*)d_in[1];
    const float* adapter = (const float*)d_in[2];
    const float* conv_w  = (const float*)d_in[3];
    const float* conv_b  = (const float*)d_in[4];
    const float* mlp_w   = (const float*)d_in[5];
    const float* mlp_b   = (const float*)d_in[6];
    float* out = (float*)d_out;

    dim3 grid(NB);     // 256 persistent blocks, 6-7 tiles each (XCD-striped)
    dim3 block(512);
    hipLaunchKernelGGL(mmf_kernel, grid, block, 0, stream,
                       feat0, feat1, adapter, conv_w, conv_b, mlp_w, mlp_b, out);
}

// Round 16
// 44.463 us; speedup vs baseline: 1.2034x; 1.0061x over previous
//
#include <hip/hip_runtime.h>

#define HW 25600
#define TS 16   // spatial locations per tile
#define NT 1600 // total tiles
#define NB 256  // persistent blocks (1 per CU; LDS forces 1 block/CU)

typedef float  f32x4   __attribute__((ext_vector_type(4)));
typedef short  short8  __attribute__((ext_vector_type(8)));
typedef short  short4v __attribute__((ext_vector_type(4)));
typedef unsigned int uint2v __attribute__((ext_vector_type(2)));
typedef unsigned int uint4v __attribute__((ext_vector_type(4)));

__device__ __forceinline__ float bf2f(short h) {
    return __builtin_bit_cast(float, (unsigned)((unsigned short)h) << 16);
}
// HW packed f32->bf16 (RNE): D.lo = bf16(a), D.hi = bf16(b)
__device__ __forceinline__ unsigned cvt_pk(float a, float b) {
    unsigned r;
    asm("v_cvt_pk_bf16_f32 %0, %1, %2" : "=v"(r) : "v"(a), "v"(b));
    return r;
}

typedef __attribute__((address_space(3))) const char lds_cchar;
typedef __attribute__((address_space(3))) char lds_char;
typedef __attribute__((address_space(1))) const void g_cvoid;
__device__ __forceinline__ unsigned lds_u32(const void* p) {
    return (unsigned)(uintptr_t)(lds_cchar*)p;
}
// Async global->LDS DMA, 16B/lane. Dest = lds_base + lane*16 (linear);
// global source address is per-lane. No VGPR destination => no spill pressure.
__device__ __forceinline__ void dma16(const float* g, unsigned lds_byte) {
    __builtin_amdgcn_global_load_lds(
        (g_cvoid*)g,
        (__attribute__((address_space(3))) void*)(lds_char*)(uintptr_t)lds_byte,
        16, 0, 0);
}

// ds_read_b64_tr_b16: lane addr = tile_base(128B-aligned) + lane16*8.
// Elem j = bf16 at tile_base + lane16*2 + j*32. offset:128 -> next 4 rows.
__device__ __forceinline__ short4v tr_read(unsigned a) {
    short4v d;
    asm volatile("ds_read_b64_tr_b16 %0, %1" : "=v"(d) : "v"(a) : "memory");
    return d;
}
__device__ __forceinline__ short4v tr_read128(unsigned a) {
    short4v d;
    asm volatile("ds_read_b64_tr_b16 %0, %1 offset:128" : "=v"(d) : "v"(a) : "memory");
    return d;
}
__device__ __forceinline__ uint4v lds_b128(unsigned a) {
    uint4v d;
    asm volatile("ds_read_b128 %0, %1" : "=v"(d) : "v"(a) : "memory");
    return d;
}
// Counted lgkm waits for the 2-deep DS pipelines (rule #18: SB(0) after).
__device__ __forceinline__ void wait_lgkm8() {
    asm volatile("s_waitcnt lgkmcnt(8)" ::: "memory");
    __builtin_amdgcn_sched_barrier(0);
}
__device__ __forceinline__ void wait_lgkm6() {
    asm volatile("s_waitcnt lgkmcnt(6)" ::: "memory");
    __builtin_amdgcn_sched_barrier(0);
}
__device__ __forceinline__ void wait_lgkm4() {
    asm volatile("s_waitcnt lgkmcnt(4)" ::: "memory");
    __builtin_amdgcn_sched_barrier(0);
}
__device__ __forceinline__ void wait_lgkm0() {
    asm volatile("s_waitcnt lgkmcnt(0)" ::: "memory");
    __builtin_amdgcn_sched_barrier(0);
}
__device__ __forceinline__ void wait_vm0() {
    asm volatile("s_waitcnt vmcnt(0)" ::: "memory");
    __builtin_amdgcn_sched_barrier(0);
}
// Barrier that drains only LDS ops; VMEM (DMA, stores) stays in flight.
__device__ __forceinline__ void bar_lgkm() {
    asm volatile("s_waitcnt lgkmcnt(0)" ::: "memory");
    __builtin_amdgcn_s_barrier();
    asm volatile("" ::: "memory");
}

// 8-read tr cluster: 4 tiles (t=0..3) x (lo, hi)
struct Clu { short4v lo0, hi0, lo1, hi1, lo2, hi2, lo3, hi3; };
__device__ __forceinline__ void issue_clu(Clu& C, unsigned base, int tstride) {
    C.lo0 = tr_read(base);                C.hi0 = tr_read128(base);
    C.lo1 = tr_read(base + tstride);      C.hi1 = tr_read128(base + tstride);
    C.lo2 = tr_read(base + 2 * tstride);  C.hi2 = tr_read128(base + 2 * tstride);
    C.lo3 = tr_read(base + 3 * tstride);  C.hi3 = tr_read128(base + 3 * tstride);
}
__device__ __forceinline__ short8 mk8(short4v lo, short4v hi) {
    return __builtin_shufflevector(lo, hi, 0, 1, 2, 3, 4, 5, 6, 7);
}

// LDS layout (bytes), 116736 total (1 block/CU):
//  Xf32 [4096] float4      0      .. 65536   DMA landing buffer (f32, linear)
//  Xbf  [4][256][16] bf16   65536  .. 98304   feats (b-major), bf16
//  fbf  [64][128]   bf16    98304  .. 114688  f (conv out), swizzle c^(s<<3)^(t<<5)
//  sc   [32][16]    f32     114688 .. 116736  attn weights
// R16: G-MFMA (f@Wm^T) moved INTO the scores phase — it reads only fbf/Xbf
// (stable since conv-end barrier), not sc. After the fused-phase barrier only
// the tiny aw-weighted epilogue remains, so the last serial region shrinks
// from ~2K cycles to ~400.
__global__ __launch_bounds__(512, 2) void mmf_kernel(
    const float* __restrict__ feat0, const float* __restrict__ feat1,
    const float* __restrict__ adapter, const float* __restrict__ conv_w,
    const float* __restrict__ conv_b, const float* __restrict__ mlp_w,
    const float* __restrict__ mlp_b, float* __restrict__ out)
{
    __shared__ __align__(128) char smem[116736];
    float* Xf32 = (float*)smem;
    short* Xbf  = (short*)(smem + 65536);
    short* fbf  = (short*)(smem + 98304);
    float* sc   = (float*)(smem + 114688);

    const int tid = threadIdx.x;
    const int bid = blockIdx.x;
    // XCD-region striping (R5): XCD k (= bid&7) owns tiles [200k, 200k+200);
    // its 32 blocks stride by 32. Adjacent tiles run on adjacent blocks of the
    // SAME XCD concurrently -> both 64B halves of each 128B HBM line are
    // consumed from one L2 fetch.
    const int xcd  = bid & 7;
    const int jb   = bid >> 3;             // 0..31 within XCD
    const int tbeg = 200 * xcd + jb;
    const int tend = 200 * (xcd + 1);
    const int w   = __builtin_amdgcn_readfirstlane(tid >> 6); // wave id
    const int l   = tid & 63;
    const int g   = l >> 4;        // k-group within fragment
    const int sl  = l & 15;        // row/col-within-tile lane index
    const int c0  = w * 16;

    const unsigned xfbase = lds_u32(Xf32);
    const unsigned xbase  = lds_u32(Xbf);
    const unsigned fbase  = lds_u32(fbf);

    // ---- DMA issue for one tile at spatial offset S (async, no waits) ------
    auto stage_dma = [&](int S) {
        #pragma unroll
        for (int i = 0; i < 8; ++i) {
            int idx = i * 512 + tid;          // [0,4096) float4 slots
            int q  = idx & 3;
            int r  = idx >> 2;
            int cc = r & 127;
            int b  = (r >> 7) & 3;
            int m  = r >> 9;                  // wave-uniform (64-slot spans)
            const float* fp = m ? feat1 : feat0;
            // dest (uniform per wave+i): lane j lands at slot i*512+w*64+j
            dma16(fp + (size_t)((b * 128 + cc) * HW + S + q * 4),
                  xfbase + (unsigned)((i * 512 + (w << 6)) << 4));
        }
    };

    // ---------------- prologue: DMA first tile; build weight fragments ------
    stage_dma(tbeg * TS);

    short8 afc[8];
    #pragma unroll
    for (int ks = 0; ks < 8; ++ks) {
        const int k0 = ks * 32 + g * 8;
        const float4 w0 = *reinterpret_cast<const float4*>(conv_w + (c0 + sl) * 256 + k0);
        const float4 w1 = *reinterpret_cast<const float4*>(conv_w + (c0 + sl) * 256 + k0 + 4);
        const float4 a0 = *reinterpret_cast<const float4*>(adapter + k0);
        const float4 a1 = *reinterpret_cast<const float4*>(adapter + k0 + 4);
        uint4v au;
        au[0] = cvt_pk(w0.x * a0.x, w0.y * a0.y);
        au[1] = cvt_pk(w0.z * a0.z, w0.w * a0.w);
        au[2] = cvt_pk(w1.x * a1.x, w1.y * a1.y);
        au[3] = cvt_pk(w1.z * a1.z, w1.w * a1.w);
        afc[ks] = __builtin_bit_cast(short8, au);
    }
    short8 afm[4];
    #pragma unroll
    for (int ks = 0; ks < 4; ++ks) {
        const int k0 = ks * 32 + g * 8;
        const float4 w0 = *reinterpret_cast<const float4*>(mlp_w + (c0 + sl) * 128 + k0);
        const float4 w1 = *reinterpret_cast<const float4*>(mlp_w + (c0 + sl) * 128 + k0 + 4);
        uint4v au;
        au[0] = cvt_pk(w0.x, w0.y);
        au[1] = cvt_pk(w0.z, w0.w);
        au[2] = cvt_pk(w1.x, w1.y);
        au[3] = cvt_pk(w1.z, w1.w);
        afm[ks] = __builtin_bit_cast(short8, au);
    }
    float bias[4], mb[4];
    #pragma unroll
    for (int i = 0; i < 4; ++i) {
        bias[i] = conv_b[c0 + g * 4 + i];
        mb[i]   = mlp_b[c0 + g * 4 + i];
    }
    wait_vm0();     // DMA(first tile) + weight loads landed
    bar_lgkm();

    for (int ti = tbeg; ti < tend; ti += 32) {
        const int S = ti * TS;

        // ---- phase 1: convert Xf32 -> Xbf[b][m*128+cc][s] bf16 (LDS->LDS) --
        // No barrier precedes this on loop re-entry (R12): convert touches
        // only Xbf (dead since the fused phase) and this wave's OWN Xf32 slots.
        #pragma unroll
        for (int i = 0; i < 8; ++i) {
            int idx = i * 512 + tid;
            const float4 v = *reinterpret_cast<const float4*>(Xf32 + (size_t)idx * 4);
            int q  = idx & 3;
            int r  = idx >> 2;
            int cc = r & 127;
            int b  = (r >> 7) & 3;
            int m  = r >> 9;
            uint2v xv;
            xv[0] = cvt_pk(v.x, v.y);
            xv[1] = cvt_pk(v.z, v.w);
            *reinterpret_cast<uint2v*>(Xbf + b * 4096 + (m * 128 + cc) * 16 + q * 4) = xv;
        }
        bar_lgkm();   // Xbf visible; Xf32 free (all waves' reads drained)

        // ---- issue DMA for next tile (lands under the compute phases) ------
        if (ti + 32 < tend) stage_dma((ti + 32) * TS);

        // ---------------- conv via MFMA, 2-deep pipelined tr clusters --------
        {
            f32x4 acc[4] = {{0,0,0,0},{0,0,0,0},{0,0,0,0},{0,0,0,0}};
            Clu cA, cB;
            issue_clu(cA, xbase + 0 * 1024 + g * 256 + sl * 8, 8192);
            #pragma unroll
            for (int ks = 0; ks < 8; ++ks) {
                Clu& cur = (ks & 1) ? cB : cA;
                Clu& nxt = (ks & 1) ? cA : cB;
                if (ks < 7) {
                    issue_clu(nxt, xbase + (ks + 1) * 1024 + g * 256 + sl * 8, 8192);
                    wait_lgkm8();
                } else {
                    wait_lgkm0();
                }
                acc[0] = __builtin_amdgcn_mfma_f32_16x16x32_bf16(afc[ks], mk8(cur.lo0, cur.hi0), acc[0], 0, 0, 0);
                acc[1] = __builtin_amdgcn_mfma_f32_16x16x32_bf16(afc[ks], mk8(cur.lo1, cur.hi1), acc[1], 0, 0, 0);
                acc[2] = __builtin_amdgcn_mfma_f32_16x16x32_bf16(afc[ks], mk8(cur.lo2, cur.hi2), acc[2], 0, 0, 0);
                acc[3] = __builtin_amdgcn_mfma_f32_16x16x32_bf16(afc[ks], mk8(cur.lo3, cur.hi3), acc[3], 0, 0, 0);
            }
            #pragma unroll
            for (int tt = 0; tt < 4; ++tt) {
                const int col = tt * 16 + sl;
                uint2v fu;
                fu[0] = cvt_pk(acc[tt][0] + bias[0], acc[tt][1] + bias[1]);
                fu[1] = cvt_pk(acc[tt][2] + bias[2], acc[tt][3] + bias[3]);
                *reinterpret_cast<uint2v*>(fbf + col * 128 + (((c0 + g * 4) ^ (sl << 3)) ^ (tt << 5))) = fu;
            }
        }
        bar_lgkm();

        // ---- fused phase: scores (MFMA+softmax+sc write) THEN G-MFMA -------
        // G reads only fbf (stable since conv-end barrier) — no dependency on
        // sc, so it needs no barrier after scores. Each wave proceeds from its
        // own softmax straight into G without waiting for other waves.
        f32x4 gacc[4] = {{0,0,0,0},{0,0,0,0},{0,0,0,0},{0,0,0,0}};
        {
            const int sm_m = w >> 2;
            const int sm_b = w & 3;
            const int ad = sl >> 2;
            const int aq = sl & 3;
            const unsigned btile = xbase + sm_b * 8192 + sm_m * 4096 + g * 256 + sl * 8;
            f32x4 accS[4] = {{0,0,0,0},{0,0,0,0},{0,0,0,0},{0,0,0,0}};
            struct SC { short4v blo, bhi; uint4v a0, a1, a2, a3; };
            SC pA, pB;
            auto issue = [&](SC& Sv, int kk) {
                const unsigned bt = btile + (unsigned)(kk * 1024);
                Sv.blo = tr_read(bt); Sv.bhi = tr_read128(bt);
                const int cg = kk * 4 + g;
                Sv.a0 = lds_b128(fbase + (unsigned)((ad * 16 + 0 + aq) * 256 + (((cg ^ (0 + aq)) ^ (ad << 2)) << 4)));
                Sv.a1 = lds_b128(fbase + (unsigned)((ad * 16 + 4 + aq) * 256 + (((cg ^ (4 + aq)) ^ (ad << 2)) << 4)));
                Sv.a2 = lds_b128(fbase + (unsigned)((ad * 16 + 8 + aq) * 256 + (((cg ^ (8 + aq)) ^ (ad << 2)) << 4)));
                Sv.a3 = lds_b128(fbase + (unsigned)((ad * 16 + 12 + aq) * 256 + (((cg ^ (12 + aq)) ^ (ad << 2)) << 4)));
            };
            issue(pA, 0);
            #pragma unroll
            for (int kk = 0; kk < 4; ++kk) {
                SC& cur = (kk & 1) ? pB : pA;
                SC& nxt = (kk & 1) ? pA : pB;
                if (kk < 3) {
                    issue(nxt, kk + 1);
                    wait_lgkm6();
                } else {
                    wait_lgkm0();
                }
                const short8 bf = mk8(cur.blo, cur.bhi);
                accS[0] = __builtin_amdgcn_mfma_f32_16x16x32_bf16(__builtin_bit_cast(short8, cur.a0), bf, accS[0], 0, 0, 0);
                accS[1] = __builtin_amdgcn_mfma_f32_16x16x32_bf16(__builtin_bit_cast(short8, cur.a1), bf, accS[1], 0, 0, 0);
                accS[2] = __builtin_amdgcn_mfma_f32_16x16x32_bf16(__builtin_bit_cast(short8, cur.a2), bf, accS[2], 0, 0, 0);
                accS[3] = __builtin_amdgcn_mfma_f32_16x16x32_bf16(__builtin_bit_cast(short8, cur.a3), bf, accS[3], 0, 0, 0);
            }
            const int cstar = sl >> 2, qstar = sl & 3;
            float x = accS[0][0];
            #pragma unroll
            for (int c = 0; c < 4; ++c)
                #pragma unroll
                for (int q = 0; q < 4; ++q)
                    if (c == cstar && q == qstar) x = accS[c][q];
            x *= 0.088388347648318447f;   // 1/sqrt(128)
            float mx = fmaxf(x, __shfl_xor(x, 16));
            mx = fmaxf(mx, __shfl_xor(mx, 32));
            float e = __expf(x - mx);
            float sm = e + __shfl_xor(e, 16);
            sm += __shfl_xor(sm, 32);
            sc[(sm_m * 16 + sm_b * 4 + g) * 16 + sl] = e / sm;

            // ---- G = f @ Wm^T (B-frags from fbf, swizzled b128 reads) ------
            struct Qu { uint4v q0, q1, q2, q3; };
            Qu qA, qB;
            auto issue_q = [&](Qu& Q, int ks) {
                const int cb = ks * 4 + g;
                Q.q0 = lds_b128(fbase + (unsigned)((0 * 16 + sl) * 256 + (((cb ^ sl) ^ 0)  << 4)));
                Q.q1 = lds_b128(fbase + (unsigned)((1 * 16 + sl) * 256 + (((cb ^ sl) ^ 4)  << 4)));
                Q.q2 = lds_b128(fbase + (unsigned)((2 * 16 + sl) * 256 + (((cb ^ sl) ^ 8)  << 4)));
                Q.q3 = lds_b128(fbase + (unsigned)((3 * 16 + sl) * 256 + (((cb ^ sl) ^ 12) << 4)));
            };
            issue_q(qA, 0);
            #pragma unroll
            for (int ks = 0; ks < 4; ++ks) {
                Qu& cur = (ks & 1) ? qB : qA;
                Qu& nxt = (ks & 1) ? qA : qB;
                if (ks < 3) {
                    issue_q(nxt, ks + 1);
                    wait_lgkm4();   // sc-write may be outstanding: older op,
                                    // in-order DS completion keeps this safe
                } else {
                    wait_lgkm0();
                }
                gacc[0] = __builtin_amdgcn_mfma_f32_16x16x32_bf16(afm[ks], __builtin_bit_cast(short8, cur.q0), gacc[0], 0, 0, 0);
                gacc[1] = __builtin_amdgcn_mfma_f32_16x16x32_bf16(afm[ks], __builtin_bit_cast(short8, cur.q1), gacc[1], 0, 0, 0);
                gacc[2] = __builtin_amdgcn_mfma_f32_16x16x32_bf16(afm[ks], __builtin_bit_cast(short8, cur.q2), gacc[2], 0, 0, 0);
                gacc[3] = __builtin_amdgcn_mfma_f32_16x16x32_bf16(afm[ks], __builtin_bit_cast(short8, cur.q3), gacc[3], 0, 0, 0);
            }
        }
        bar_lgkm();   // all sc writes visible

        // ---- epilogue: aw-weighted sum + relu + residual + out --------------
        {
            // gacc[dd][i] = G[c0+g*4+i][col = dd*16+sl]
            float aw_[4][4];
            #pragma unroll
            for (int b = 0; b < 4; ++b)
                #pragma unroll
                for (int d = 0; d < 4; ++d)
                    aw_[b][d] = sc[(b * 4 + d) * 16 + sl] + sc[256 + (b * 4 + d) * 16 + sl];
            // Drain the next tile's DMA BEFORE issuing stores: per-wave vmcnt
            // then counts only DMA (stores not yet issued). The stores below
            // run unwaited and overlap the next tile's convert+conv phases.
            wait_vm0();
            #pragma unroll
            for (int b = 0; b < 4; ++b) {
                const int col = b * 16 + sl;
                const short4v res = *reinterpret_cast<const short4v*>(
                    fbf + col * 128 + (((c0 + g * 4) ^ (sl << 3)) ^ (b << 5)));
                #pragma unroll
                for (int i = 0; i < 4; ++i) {
                    float v = mb[i];
                    #pragma unroll
                    for (int d = 0; d < 4; ++d) v += aw_[b][d] * gacc[d][i];
                    const int c = c0 + g * 4 + i;
                    out[(size_t)(b * 128 + c) * HW + S + sl] =
                        fmaxf(v, 0.f) + bf2f(res[i]);
                }
            }
        }
        // No end-of-tile barrier (R12): next convert touches only Xbf (dead —
        // its last readers were the fused phase's tr_reads, drained before the
        // fused-end barrier) + this wave's own Xf32 slots (DMA drained by
        // wait_vm0 above). fbf/sc are next WRITTEN only after the convert-end
        // (resp. conv-end) barrier.
    }
}

extern "C" void kernel_launch(void* const* d_in, const int* in_sizes, int n_in,
                              void* d_out, int out_size, void* d_ws, size_t ws_size,
                              hipStream_t stream) {
    const float* feat0   = (const float*)d_in[0];
    const float* feat1   = (const float*)d_in[1];
    const float* adapter = (const float*)d_in[2];
    const float* conv_w  = (const float*)d_in[3];
    const float* conv_b  = (const float*)d_in[4];
    const float* mlp_w   = (const float*)d_in[5];
    const float* mlp_b   = (const float*)d_in[6];
    float* out = (float*)d_out;

    dim3 grid(NB);     // 256 persistent blocks, 6-7 tiles each (XCD-striped)
    dim3 block(512);
    hipLaunchKernelGGL(mmf_kernel, grid, block, 0, stream,
                       feat0, feat1, adapter, conv_w, conv_b, mlp_w, mlp_b, out);
}